// Round 4
// baseline (344.784 us; speedup 1.0000x reference)
//
#include <hip/hip_runtime.h>
#include <hip/hip_bf16.h>

#define BB     8
#define CC     320
#define NN     4096
#define SKV    77
#define HEADS  8
#define DH     64
#define INNER  512
#define SCALE  0.125f

typedef float f32x4  __attribute__((ext_vector_type(4)));
typedef short bf16x8 __attribute__((ext_vector_type(8)));
typedef short s16x4  __attribute__((ext_vector_type(4)));

static __device__ __forceinline__ short f2bf(float f) {
  unsigned u = __float_as_uint(f);
  return (short)((u + 0x7fffu + ((u >> 16) & 1u)) >> 16);
}

// ---------------------------------------------------------------------------
// prep: conversions/transposes to bf16.
// blocks: [0,616) kv | [616,872) Wk/Wv 64x64 transpose tiles |
// [872,1032) Wq elementwise | [1032,1072) Wo transpose tiles
// ---------------------------------------------------------------------------
__global__ __launch_bounds__(256) void prep_kernel(
    const float* __restrict__ kv, const float* __restrict__ Wk,
    const float* __restrict__ Wv, const float* __restrict__ Wq,
    const float* __restrict__ Wo, short* __restrict__ kv_bf,
    short* __restrict__ Wk_t, short* __restrict__ Wv_t,
    short* __restrict__ Wq_bf, short* __restrict__ Wo_t) {
  __shared__ float T[64 * 65];
  const int blk = blockIdx.x, t = threadIdx.x;
  if (blk < 616) {
    const int base = blk * 1024;
    #pragma unroll
    for (int i = 0; i < 4; ++i) kv_bf[base + i*256 + t] = f2bf(kv[base + i*256 + t]);
  } else if (blk < 872) {
    // 64x64 tile transpose: src [1024][512] -> dst [512][1024]
    const int tile = blk - 616;
    const bool isK = tile < 128;
    const int tt = isK ? tile : tile - 128;
    const int kt = tt >> 3, ct = tt & 7;
    const float* __restrict__ src = isK ? Wk : Wv;
    short* __restrict__ dst = isK ? Wk_t : Wv_t;
    const int cl = t & 63, rb = t >> 6;
    #pragma unroll
    for (int i = 0; i < 16; ++i)
      T[(rb + i*4)*65 + cl] = src[(size_t)(kt*64 + rb + i*4)*512 + ct*64 + cl];
    __syncthreads();
    #pragma unroll
    for (int i = 0; i < 16; ++i) {
      const int nl = rb + i*4;
      dst[(size_t)(ct*64 + nl)*1024 + kt*64 + cl] = f2bf(T[cl*65 + nl]);
    }
  } else if (blk < 1032) {
    const int base = (blk - 872) * 1024;
    #pragma unroll
    for (int i = 0; i < 4; ++i) Wq_bf[base + i*256 + t] = f2bf(Wq[base + i*256 + t]);
  } else {
    // Wo [512][320] -> Wo_t [320][512], 64x64 tiles: 8 kt x 5 ct
    const int tile = blk - 1032;
    const int kt = tile / 5, ct = tile % 5;
    const int cl = t & 63, rb = t >> 6;
    #pragma unroll
    for (int i = 0; i < 16; ++i)
      T[(rb + i*4)*65 + cl] = Wo[(size_t)(kt*64 + rb + i*4)*320 + ct*64 + cl];
    __syncthreads();
    #pragma unroll
    for (int i = 0; i < 16; ++i) {
      const int nl = rb + i*4;
      Wo_t[(size_t)(ct*64 + nl)*512 + kt*64 + cl] = f2bf(T[cl*65 + nl]);
    }
  }
}

// ---------------------------------------------------------------------------
// kvfold: per (b,h): project K (or V) from kv, then fold with Wq (or Wo):
//   path 0: K = kv_b @ Wk_h  -> LDS;  M_T[s][c] = sum_d K[s][d]*Wq[c][h*64+d]
//   path 1: V = kv_b @ Wv_h  -> LDS;  W2_T[c][s] = sum_d Wo_t[c][h*64+d]*V[s][d]
// grid (64 bh, 2 path). LDS rows >=77 zeroed -> M_T rows 77-79 and W2_T cols
// 77-95 are exactly 0 (no NaN propagation).
// ---------------------------------------------------------------------------
__global__ __launch_bounds__(256) void kvfold_kernel(
    const short* __restrict__ kv_bf, const short* __restrict__ Wk_t,
    const short* __restrict__ Wv_t, const short* __restrict__ Wq_bf,
    const short* __restrict__ Wo_t, short* __restrict__ M_T,
    short* __restrict__ W2_T) {
  const int bh = blockIdx.x;
  const int path = blockIdx.y;
  const int b = bh >> 3, h = bh & 7;
  const int t = threadIdx.x, w = t >> 6, lane = t & 63;
  const int l15 = lane & 15, q = lane >> 4;
  __shared__ short sv[96 * 72];
  for (int i = t; i < 96*72/2; i += 256) ((unsigned*)sv)[i] = 0u;
  __syncthreads();

  const f32x4 z = {0.f, 0.f, 0.f, 0.f};
  const short* __restrict__ Wt = path ? Wv_t : Wk_t;

  {  // phase A: projection; wave w -> d-cols [w*16, w*16+16)
    f32x4 acc[5] = {z, z, z, z, z};
    for (int ks = 0; ks < 32; ++ks) {
      const bf16x8 bf = *(const bf16x8*)(Wt + (h*64 + w*16 + l15)*1024 + ks*32 + q*8);
      #pragma unroll
      for (int mt = 0; mt < 5; ++mt) {
        const int s = mt*16 + l15;
        const int srow = b*77 + (s < 77 ? s : 76);
        const bf16x8 a = *(const bf16x8*)(kv_bf + srow*1024 + ks*32 + q*8);
        acc[mt] = __builtin_amdgcn_mfma_f32_16x16x32_bf16(a, bf, acc[mt], 0, 0, 0);
      }
    }
    #pragma unroll
    for (int mt = 0; mt < 5; ++mt)
      #pragma unroll
      for (int r = 0; r < 4; ++r) {
        const int s = mt*16 + q*4 + r;
        if (s < 77) sv[s*72 + w*16 + l15] = f2bf(acc[mt][r]);
      }
  }
  __syncthreads();

  if (path == 0) {
    // M_T[s][c]: A = sv(K) [m=s][k=d], B = Wq rows (c) [k=d][n=c]
    f32x4 acc[5][5];
    #pragma unroll
    for (int mt = 0; mt < 5; ++mt)
      #pragma unroll
      for (int nt = 0; nt < 5; ++nt) acc[mt][nt] = z;
    #pragma unroll
    for (int ks = 0; ks < 2; ++ks) {
      bf16x8 a[5];
      #pragma unroll
      for (int mt = 0; mt < 5; ++mt)
        a[mt] = *(const bf16x8*)(sv + (mt*16 + l15)*72 + ks*32 + q*8);
      #pragma unroll
      for (int nt = 0; nt < 5; ++nt) {
        const int c = (w*5 + nt)*16 + l15;
        const bf16x8 bq = *(const bf16x8*)(Wq_bf + c*512 + h*64 + ks*32 + q*8);
        #pragma unroll
        for (int mt = 0; mt < 5; ++mt)
          acc[mt][nt] = __builtin_amdgcn_mfma_f32_16x16x32_bf16(a[mt], bq, acc[mt][nt], 0, 0, 0);
      }
    }
    #pragma unroll
    for (int mt = 0; mt < 5; ++mt)
      #pragma unroll
      for (int nt = 0; nt < 5; ++nt)
        #pragma unroll
        for (int r = 0; r < 4; ++r)
          M_T[(size_t)(bh*80 + mt*16 + q*4 + r)*320 + (w*5 + nt)*16 + l15] = f2bf(acc[mt][nt][r]);
  } else {
    // W2_T[c][s]: A = Wo_t rows (c, wave's 5 m-tiles), B = sv(V) [k=d][n=s]
    f32x4 acc[5][6];
    #pragma unroll
    for (int mt = 0; mt < 5; ++mt)
      #pragma unroll
      for (int nt = 0; nt < 6; ++nt) acc[mt][nt] = z;
    #pragma unroll
    for (int ks = 0; ks < 2; ++ks) {
      bf16x8 bv[6];
      #pragma unroll
      for (int nt = 0; nt < 6; ++nt)
        bv[nt] = *(const bf16x8*)(sv + (nt*16 + l15)*72 + ks*32 + q*8);
      #pragma unroll
      for (int mt = 0; mt < 5; ++mt) {
        const int c = (w*5 + mt)*16 + l15;
        const bf16x8 a = *(const bf16x8*)(Wo_t + c*512 + h*64 + ks*32 + q*8);
        #pragma unroll
        for (int nt = 0; nt < 6; ++nt)
          acc[mt][nt] = __builtin_amdgcn_mfma_f32_16x16x32_bf16(a, bv[nt], acc[mt][nt], 0, 0, 0);
      }
    }
    #pragma unroll
    for (int mt = 0; mt < 5; ++mt)
      #pragma unroll
      for (int nt = 0; nt < 6; ++nt)
        #pragma unroll
        for (int r = 0; r < 4; ++r)
          W2_T[(size_t)(bh*320 + (w*5 + mt)*16 + q*4 + r)*96 + nt*16 + l15] = f2bf(acc[mt][nt][r]);
  }
}

// ---------------------------------------------------------------------------
// attn: per block (b, 64 tokens); wave w owns tokens w*16+l15.
//   X staged in 64-channel chunks -> xf[10] registers (held whole kernel).
//   Per head: S^T = M_T @ X^T (50 MFMA, tables from L1/L2) -> shfl softmax ->
//   P packed to per-wave LDS -> out^T += W2_T @ P (60 MFMA, fp32 acc over
//   heads). One barrier per head (phase alignment for L1 sharing only).
// ---------------------------------------------------------------------------
__global__ __launch_bounds__(256) void attn_kernel(
    const float* __restrict__ query, const short* __restrict__ M_T,
    const short* __restrict__ W2_T, const float* __restrict__ bo,
    float* __restrict__ out) {
  const int n0 = blockIdx.x * 64;
  const int b  = blockIdx.y;
  const int t = threadIdx.x, w = t >> 6, lane = t & 63;
  const int l15 = lane & 15, q = lane >> 4;

  __shared__ short smem[9216 + 6656];     // stage[64][72] + pw 4x[16][104] = 31.7KB
  short* stage = smem;
  short* pw = smem + 9216 + w * 16 * 104;

  // ---- stage X in 5 chunks of 64 channels; hoist fragments to registers ----
  bf16x8 xf[10];
  for (int cc = 0; cc < 5; ++cc) {
    if (cc) __syncthreads();
    {
      const int tok = t & 63, cb = t >> 6;   // tok == lane
      #pragma unroll
      for (int i = 0; i < 16; ++i) {
        const int c = cb + i*4;
        stage[tok*72 + c] = f2bf(query[((size_t)(b*CC + cc*64 + c))*NN + n0 + tok]);
      }
    }
    __syncthreads();
    #pragma unroll
    for (int s2 = 0; s2 < 2; ++s2)
      xf[cc*2 + s2] = *(const bf16x8*)(stage + (w*16 + l15)*72 + s2*32 + q*8);
  }

  // zero own P region (cols [80,96) stay 0 forever; [0,80) rewritten per head)
  for (int i = lane; i < 832; i += 64) ((unsigned*)pw)[i] = 0u;

  const f32x4 z = {0.f, 0.f, 0.f, 0.f};
  f32x4 outacc[20];
  #pragma unroll
  for (int mt = 0; mt < 20; ++mt) outacc[mt] = z;

  for (int h = 0; h < HEADS; ++h) {
    __syncthreads();   // phase-align waves so table reads share L1
    const short* __restrict__ Mt = M_T  + (size_t)(b*8 + h) * 80 * 320;
    const short* __restrict__ W2 = W2_T + (size_t)(b*8 + h) * 320 * 96;

    // ---- S^T[s][tok] = M_T @ X^T (xf registers are the B operand) ----
    f32x4 qk[5] = {z, z, z, z, z};
    #pragma unroll
    for (int ks = 0; ks < 10; ++ks) {
      #pragma unroll
      for (int mt = 0; mt < 5; ++mt) {
        const bf16x8 a = *(const bf16x8*)(Mt + (mt*16 + l15)*320 + ks*32 + q*8);
        qk[mt] = __builtin_amdgcn_mfma_f32_16x16x32_bf16(a, xf[ks], qk[mt], 0, 0, 0);
      }
    }

    // ---- softmax over s (lane: tok=l15 fixed, s = mt*16+q*4+r) ----
    float mx = -1e30f;
    #pragma unroll
    for (int mt = 0; mt < 5; ++mt)
      #pragma unroll
      for (int r = 0; r < 4; ++r) {
        const int s = mt*16 + q*4 + r;
        const float vv = (s < SKV) ? qk[mt][r] * SCALE : -1e30f;
        qk[mt][r] = vv;
        mx = fmaxf(mx, vv);
      }
    mx = fmaxf(mx, __shfl_xor(mx, 16));
    mx = fmaxf(mx, __shfl_xor(mx, 32));
    float sum = 0.f;
    #pragma unroll
    for (int mt = 0; mt < 5; ++mt)
      #pragma unroll
      for (int r = 0; r < 4; ++r) {
        const int s = mt*16 + q*4 + r;
        const float e = (s < SKV) ? __expf(qk[mt][r] - mx) : 0.f;
        qk[mt][r] = e;
        sum += e;
      }
    sum += __shfl_xor(sum, 16);
    sum += __shfl_xor(sum, 32);
    const float inv = 1.0f / sum;
    // packed conflict-free writes: 4 consecutive s per lane (zeros cover 77..79)
    #pragma unroll
    for (int mt = 0; mt < 5; ++mt) {
      s16x4 pv;
      #pragma unroll
      for (int r = 0; r < 4; ++r) pv[r] = f2bf(qk[mt][r] * inv);
      *(s16x4*)(pw + l15*104 + mt*16 + q*4) = pv;
    }

    // ---- out^T[c][tok] += W2_T @ P (B-frag = row-read of pw) ----
    #pragma unroll
    for (int ks = 0; ks < 3; ++ks) {
      const bf16x8 bp = *(const bf16x8*)(pw + l15*104 + ks*32 + q*8);
      #pragma unroll
      for (int mt = 0; mt < 20; ++mt) {
        const bf16x8 a = *(const bf16x8*)(W2 + (mt*16 + l15)*96 + ks*32 + q*8);
        outacc[mt] = __builtin_amdgcn_mfma_f32_16x16x32_bf16(a, bp, outacc[mt], 0, 0, 0);
      }
    }
  }

  // ---- epilogue: bias + store out[b][c][n0 + w*16 + l15] ----
  #pragma unroll
  for (int mt = 0; mt < 20; ++mt)
    #pragma unroll
    for (int r = 0; r < 4; ++r) {
      const int c = mt*16 + q*4 + r;
      out[((size_t)(b*CC + c))*NN + n0 + w*16 + l15] = outacc[mt][r] + bo[c];
    }
}

// ---------------------------------------------------------------------------
extern "C" void kernel_launch(void* const* d_in, const int* in_sizes, int n_in,
                              void* d_out, int out_size, void* d_ws, size_t ws_size,
                              hipStream_t stream) {
  const float* query = (const float*)d_in[0];
  const float* kv    = (const float*)d_in[1];
  const float* Wq    = (const float*)d_in[2];
  const float* Wk    = (const float*)d_in[3];
  const float* Wv    = (const float*)d_in[4];
  const float* Wo    = (const float*)d_in[5];
  const float* bo    = (const float*)d_in[6];
  float* out = (float*)d_out;

  char* p = (char*)d_ws;
  short* M_T   = (short*)(p);             // 3,276,800 B [64][80][320]
  short* W2_T  = (short*)(p +  3276800);  // 3,932,160 B [64][320][96]
  short* kv_bf = (short*)(p +  7208960);  // 1,261,568 B [616][1024]
  short* Wk_t  = (short*)(p +  8470528);  // 1,048,576 B [512][1024]
  short* Wv_t  = (short*)(p +  9519104);  // 1,048,576 B [512][1024]
  short* Wq_bf = (short*)(p + 10567680);  //   327,680 B [320][512]
  short* Wo_t  = (short*)(p + 10895360);  //   327,680 B [320][512]

  prep_kernel<<<1072, 256, 0, stream>>>(kv, Wk, Wv, Wq, Wo, kv_bf, Wk_t, Wv_t,
                                        Wq_bf, Wo_t);
  kvfold_kernel<<<dim3(64, 2), 256, 0, stream>>>(kv_bf, Wk_t, Wv_t, Wq_bf, Wo_t,
                                                 M_T, W2_T);
  attn_kernel<<<dim3(64, 8), 256, 0, stream>>>(query, M_T, W2_T, bo, out);
}

// Round 5
// 337.850 us; speedup vs baseline: 1.0205x; 1.0205x over previous
//
#include <hip/hip_runtime.h>
#include <hip/hip_bf16.h>

#define BB     8
#define CC     320
#define NN     4096
#define SKV    77
#define HEADS  8
#define DH     64
#define INNER  512
#define SCALE  0.125f
#define SSTR   120   // scratch row stride (shorts): 240 B -> 16B-aligned rows

typedef float f32x4  __attribute__((ext_vector_type(4)));
typedef short bf16x8 __attribute__((ext_vector_type(8)));
typedef short s16x4  __attribute__((ext_vector_type(4)));

static __device__ __forceinline__ short f2bf(float f) {
  unsigned u = __float_as_uint(f);
  return (short)((u + 0x7fffu + ((u >> 16) & 1u)) >> 16);
}

// ---------------------------------------------------------------------------
// prep: kv->bf16 | Wk,Wv tiled transpose->bf16 | Wq_t,Wo_t | zero K_ws/V_ws.
// blocks: [0,616) kv | [616,872) Wk/Wv tiles | [872,1384) Wq_t |
// [1384,1704) Wo_t | [1704,2144) zero K_ws+V_ws (1,802,240 B)
// ---------------------------------------------------------------------------
__global__ __launch_bounds__(256) void prep_kernel(
    const float* __restrict__ kv, const float* __restrict__ Wk,
    const float* __restrict__ Wv, const float* __restrict__ Wq,
    const float* __restrict__ Wo, short* __restrict__ kv_bf,
    short* __restrict__ Wk_t, short* __restrict__ Wv_t,
    short* __restrict__ Wq_t, short* __restrict__ Wo_t,
    unsigned* __restrict__ zero_base) {
  __shared__ float T[64 * 65];
  const int blk = blockIdx.x, t = threadIdx.x;
  if (blk < 616) {
    const int base = blk * 1024;
    #pragma unroll
    for (int i = 0; i < 4; ++i) kv_bf[base + i*256 + t] = f2bf(kv[base + i*256 + t]);
  } else if (blk < 872) {
    // 64x64 tile transpose: src [1024][512] -> dst [512][1024]
    const int tile = blk - 616;
    const bool isK = tile < 128;
    const int tt = isK ? tile : tile - 128;
    const int kt = tt >> 3, ct = tt & 7;
    const float* __restrict__ src = isK ? Wk : Wv;
    short* __restrict__ dst = isK ? Wk_t : Wv_t;
    const int cl = t & 63, rb = t >> 6;
    #pragma unroll
    for (int i = 0; i < 16; ++i)
      T[(rb + i*4)*65 + cl] = src[(size_t)(kt*64 + rb + i*4)*512 + ct*64 + cl];
    __syncthreads();
    #pragma unroll
    for (int i = 0; i < 16; ++i) {
      const int nl = rb + i*4;
      dst[(size_t)(ct*64 + nl)*1024 + kt*64 + cl] = f2bf(T[cl*65 + nl]);
    }
  } else if (blk < 1384) {
    const int n = blk - 872;
    for (int c = t; c < 320; c += 256) Wq_t[n*320 + c] = f2bf(Wq[c*512 + n]);
  } else if (blk < 1704) {
    const int c = blk - 1384;
    for (int j = t; j < 512; j += 256) Wo_t[c*512 + j] = f2bf(Wo[j*320 + c]);
  } else {
    const int base = (blk - 1704) * 1024;
    #pragma unroll
    for (int i = 0; i < 4; ++i) zero_base[base + i*256 + t] = 0u;
  }
}

// ---------------------------------------------------------------------------
// kvproj: [616,1024]bf16 @ Wk_t/Wv_t -> K_ws [b][h][80][64], V_ws [b][h][64][96]
// (rows/cols s>=77 remain zero from prep's zeroing pass)
// ---------------------------------------------------------------------------
__global__ __launch_bounds__(256) void kvproj_kernel(
    const short* __restrict__ kv_bf, const short* __restrict__ Wk_t,
    const short* __restrict__ Wv_t, short* __restrict__ K_ws,
    short* __restrict__ V_ws) {
  const int t = threadIdx.x, w = t >> 6, lane = t & 63;
  const int l15 = lane & 15, q = lane >> 4;
  const int m0 = (blockIdx.x * 4 + w) * 16;
  const int y = blockIdx.y;
  const bool isK = (y < 8);
  const int h = y & 7;
  const short* __restrict__ Wt = isK ? Wk_t : Wv_t;
  const int arow = (m0 + l15 < 616) ? (m0 + l15) : 615;

  const f32x4 z = {0.f, 0.f, 0.f, 0.f};
  f32x4 acc[4] = {z, z, z, z};
  for (int k0 = 0; k0 < 1024; k0 += 32) {
    const bf16x8 a = *(const bf16x8*)(kv_bf + arow*1024 + k0 + q*8);
    #pragma unroll
    for (int nt = 0; nt < 4; ++nt) {
      const int n = h*64 + nt*16 + l15;
      const bf16x8 bfr = *(const bf16x8*)(Wt + n*1024 + k0 + q*8);
      acc[nt] = __builtin_amdgcn_mfma_f32_16x16x32_bf16(a, bfr, acc[nt], 0, 0, 0);
    }
  }
  #pragma unroll
  for (int nt = 0; nt < 4; ++nt) {
    const int d = nt*16 + l15;
    #pragma unroll
    for (int r = 0; r < 4; ++r) {
      const int row = m0 + q*4 + r;
      if (row < 616) {
        const int b = (int)(((unsigned)row * 54472u) >> 22);   // row/77
        const int s = row - b*77;
        if (isK) K_ws[((b*8 + h)*80 + s)*64 + d] = f2bf(acc[nt][r]);
        else     V_ws[((b*8 + h)*64 + d)*96 + s] = f2bf(acc[nt][r]);
      }
    }
  }
}

// ---------------------------------------------------------------------------
// attn: ONE WAVE per block, 16 tokens, all 8 heads, zero barriers.
//   xf[10]: X^T B-layout fragments in registers (read native query layout).
//   Per head: Qproj D[d][tok] (A=Wq_t) -> scratch -> QK^T D[s][tok] (A=K_ws)
//   -> shfl softmax -> P -> scratch -> PV D[d][tok] (A=V_ws) -> scratch ->
//   outproj accumulate over heads (A=Wo_t, outacc[20] fp32).
//   All C->B relayouts via per-wave LDS scratch (same-wave lgkm ordering,
//   no __syncthreads anywhere). Tables K/V/Wq/Wo ~2.4 MB: L2-resident.
// ---------------------------------------------------------------------------
__global__ __launch_bounds__(64, 3) void attn_kernel(
    const float* __restrict__ query, const short* __restrict__ Wq_t,
    const short* __restrict__ K_ws, const short* __restrict__ V_ws,
    const short* __restrict__ Wo_t, const float* __restrict__ bo,
    float* __restrict__ out) {
  const int b  = blockIdx.x >> 8;
  const int n0 = (blockIdx.x & 255) * 16;
  const int lane = threadIdx.x;
  const int l15 = lane & 15, q = lane >> 4;

  __shared__ short scr[16 * SSTR];   // 3840 B per-wave scratch
  // zero once: pad cols [80,96) must be 0 for P reads; rest overwritten
  for (int i = lane; i < 16*SSTR/2; i += 64) ((unsigned*)scr)[i] = 0u;
  short* srow = scr + l15 * SSTR;

  // ---- xf: B-layout fragments of X^T (k=c=ks*32+q*8+j, n=tok=n0+l15) ----
  bf16x8 xf[10];
  #pragma unroll
  for (int ks = 0; ks < 10; ++ks) {
    const float* qp = query + ((size_t)b*CC + ks*32 + q*8)*NN + n0 + l15;
    bf16x8 v;
    #pragma unroll
    for (int j = 0; j < 8; ++j) v[j] = f2bf(qp[(size_t)j*NN]);
    xf[ks] = v;
  }

  const f32x4 z = {0.f, 0.f, 0.f, 0.f};
  f32x4 outacc[20];
  #pragma unroll
  for (int mt = 0; mt < 20; ++mt) outacc[mt] = z;

  #pragma unroll 1
  for (int h = 0; h < HEADS; ++h) {
    const short* __restrict__ Wqh = Wq_t + (size_t)(h*64) * 320;
    const short* __restrict__ Kh  = K_ws + (size_t)(b*8 + h) * 80 * 64;
    const short* __restrict__ Vh  = V_ws + (size_t)(b*8 + h) * 64 * 96;

    // ---- Qproj: D[d][tok] = Wq_h^T @ X^T ----
    f32x4 qa[4] = {z, z, z, z};
    #pragma unroll
    for (int ks = 0; ks < 10; ++ks) {
      #pragma unroll
      for (int dt = 0; dt < 4; ++dt) {
        const bf16x8 a = *(const bf16x8*)(Wqh + (dt*16 + l15)*320 + ks*32 + q*8);
        qa[dt] = __builtin_amdgcn_mfma_f32_16x16x32_bf16(a, xf[ks], qa[dt], 0, 0, 0);
      }
    }
    #pragma unroll
    for (int dt = 0; dt < 4; ++dt) {      // scratch[tok][d] <- Q^T
      s16x4 pv;
      #pragma unroll
      for (int r = 0; r < 4; ++r) pv[r] = f2bf(qa[dt][r]);
      *(s16x4*)(srow + dt*16 + q*4) = pv;
    }

    // ---- QK^T: D[s][tok] = K @ Q^T (B = scratch row-read) ----
    f32x4 qk[5] = {z, z, z, z, z};
    #pragma unroll
    for (int f = 0; f < 2; ++f) {
      const bf16x8 bq = *(const bf16x8*)(srow + f*32 + q*8);
      #pragma unroll
      for (int st = 0; st < 5; ++st) {
        const bf16x8 a = *(const bf16x8*)(Kh + (st*16 + l15)*64 + f*32 + q*8);
        qk[st] = __builtin_amdgcn_mfma_f32_16x16x32_bf16(a, bq, qk[st], 0, 0, 0);
      }
    }

    // ---- softmax over s (tok=l15 fixed; s = st*16+q*4+r; quad reduce) ----
    float mx = -1e30f;
    #pragma unroll
    for (int st = 0; st < 5; ++st)
      #pragma unroll
      for (int r = 0; r < 4; ++r) {
        const int s = st*16 + q*4 + r;
        const float vv = (s < SKV) ? qk[st][r] * SCALE : -1e30f;
        qk[st][r] = vv;
        mx = fmaxf(mx, vv);
      }
    mx = fmaxf(mx, __shfl_xor(mx, 16));
    mx = fmaxf(mx, __shfl_xor(mx, 32));
    float sum = 0.f;
    #pragma unroll
    for (int st = 0; st < 5; ++st)
      #pragma unroll
      for (int r = 0; r < 4; ++r) {
        const int s = st*16 + q*4 + r;
        const float e = (s < SKV) ? __expf(qk[st][r] - mx) : 0.f;
        qk[st][r] = e;
        sum += e;
      }
    sum += __shfl_xor(sum, 16);
    sum += __shfl_xor(sum, 32);
    const float inv = 1.0f / sum;
    #pragma unroll
    for (int st = 0; st < 5; ++st) {      // scratch[tok][s] <- P (cols 0..79)
      s16x4 pv;
      #pragma unroll
      for (int r = 0; r < 4; ++r) pv[r] = f2bf(qk[st][r] * inv);
      *(s16x4*)(srow + st*16 + q*4) = pv;
    }

    // ---- PV: D[d][tok] = V^T @ P^T (B = scratch, cols 0..95, pad=0) ----
    f32x4 ov[4] = {z, z, z, z};
    #pragma unroll
    for (int f = 0; f < 3; ++f) {
      const bf16x8 bp = *(const bf16x8*)(srow + f*32 + q*8);
      #pragma unroll
      for (int dt = 0; dt < 4; ++dt) {
        const bf16x8 a = *(const bf16x8*)(Vh + (dt*16 + l15)*96 + f*32 + q*8);
        ov[dt] = __builtin_amdgcn_mfma_f32_16x16x32_bf16(a, bp, ov[dt], 0, 0, 0);
      }
    }
    #pragma unroll
    for (int dt = 0; dt < 4; ++dt) {      // scratch[tok][d] <- O^T
      s16x4 pv;
      #pragma unroll
      for (int r = 0; r < 4; ++r) pv[r] = f2bf(ov[dt][r]);
      *(s16x4*)(srow + dt*16 + q*4) = pv;
    }

    // ---- outproj: out^T[c][tok] += Wo_h^T @ O (accumulate over heads) ----
    #pragma unroll
    for (int f = 0; f < 2; ++f) {
      const bf16x8 bfr = *(const bf16x8*)(srow + f*32 + q*8);
      #pragma unroll
      for (int mt = 0; mt < 20; ++mt) {
        const bf16x8 a = *(const bf16x8*)(Wo_t + (mt*16 + l15)*512 + h*64 + f*32 + q*8);
        outacc[mt] = __builtin_amdgcn_mfma_f32_16x16x32_bf16(a, bfr, outacc[mt], 0, 0, 0);
      }
    }
  }

  // ---- epilogue: bias + store out[b][c][n0 + l15] ----
  #pragma unroll
  for (int mt = 0; mt < 20; ++mt)
    #pragma unroll
    for (int r = 0; r < 4; ++r) {
      const int c = mt*16 + q*4 + r;
      out[((size_t)(b*CC + c))*NN + n0 + l15] = outacc[mt][r] + bo[c];
    }
}

// ---------------------------------------------------------------------------
extern "C" void kernel_launch(void* const* d_in, const int* in_sizes, int n_in,
                              void* d_out, int out_size, void* d_ws, size_t ws_size,
                              hipStream_t stream) {
  const float* query = (const float*)d_in[0];
  const float* kv    = (const float*)d_in[1];
  const float* Wq    = (const float*)d_in[2];
  const float* Wk    = (const float*)d_in[3];
  const float* Wv    = (const float*)d_in[4];
  const float* Wo    = (const float*)d_in[5];
  const float* bo    = (const float*)d_in[6];
  float* out = (float*)d_out;

  char* p = (char*)d_ws;
  short* K_ws  = (short*)(p);             //   819,200 B [8][8][80][64]
  short* V_ws  = (short*)(p +   819200);  //   983,040 B [8][8][64][96]
  short* kv_bf = (short*)(p +  1802240);  // 1,261,568 B [616][1024]
  short* Wk_t  = (short*)(p +  3063808);  // 1,048,576 B [512][1024]
  short* Wv_t  = (short*)(p +  4112384);  // 1,048,576 B [512][1024]
  short* Wq_t  = (short*)(p +  5160960);  //   327,680 B [512][320]
  short* Wo_t  = (short*)(p +  5488640);  //   327,680 B [320][512]

  prep_kernel<<<2144, 256, 0, stream>>>(kv, Wk, Wv, Wq, Wo, kv_bf, Wk_t, Wv_t,
                                        Wq_t, Wo_t, (unsigned*)p);
  kvproj_kernel<<<dim3(10, 16), 256, 0, stream>>>(kv_bf, Wk_t, Wv_t, K_ws, V_ws);
  attn_kernel<<<2048, 64, 0, stream>>>(query, Wq_t, K_ws, V_ws, Wo_t, bo, out);
}

// Round 6
// 273.142 us; speedup vs baseline: 1.2623x; 1.2369x over previous
//
#include <hip/hip_runtime.h>
#include <hip/hip_bf16.h>

#define BB     8
#define CC     320
#define NN     4096
#define SKV    77
#define HEADS  8
#define DH     64
#define INNER  512
#define SCALE  0.125f

typedef float f32x4  __attribute__((ext_vector_type(4)));
typedef short bf16x8 __attribute__((ext_vector_type(8)));
typedef short s16x4  __attribute__((ext_vector_type(4)));

static __device__ __forceinline__ short f2bf(float f) {
  unsigned u = __float_as_uint(f);
  return (short)((u + 0x7fffu + ((u >> 16) & 1u)) >> 16);
}

// ---------------------------------------------------------------------------
// prep: kv->bf16 | Wk,Wv,Wq,Wo tiled transposes -> bf16 | zero K_ws/V_ws.
// blocks: [0,616) kv | [616,872) Wk/Wv 64x64 tiles | [872,912) Wq tiles |
// [912,952) Wo tiles | [952,1392) zero K_ws+V_ws (1,802,240 B)
// ---------------------------------------------------------------------------
__global__ __launch_bounds__(256) void prep_kernel(
    const float* __restrict__ kv, const float* __restrict__ Wk,
    const float* __restrict__ Wv, const float* __restrict__ Wq,
    const float* __restrict__ Wo, short* __restrict__ kv_bf,
    short* __restrict__ Wk_t, short* __restrict__ Wv_t,
    short* __restrict__ Wq_t, short* __restrict__ Wo_t,
    unsigned* __restrict__ zero_base) {
  __shared__ float T[64 * 65];
  const int blk = blockIdx.x, t = threadIdx.x;
  if (blk < 616) {
    const int base = blk * 1024;
    #pragma unroll
    for (int i = 0; i < 4; ++i) kv_bf[base + i*256 + t] = f2bf(kv[base + i*256 + t]);
    return;
  }
  if (blk >= 952) {
    const int base = (blk - 952) * 1024;
    #pragma unroll
    for (int i = 0; i < 4; ++i) zero_base[base + i*256 + t] = 0u;
    return;
  }
  // tiled transpose src[RS][CS] -> dst[CS][RS]
  const float* src; short* dst; int RS, CS, kt, ct;
  if (blk < 872) {               // Wk/Wv: [1024][512] -> [512][1024]
    const int tile = blk - 616;
    const bool isK = tile < 128;
    const int tt = isK ? tile : tile - 128;
    src = isK ? Wk : Wv; dst = isK ? Wk_t : Wv_t;
    RS = 1024; CS = 512; kt = tt >> 3; ct = tt & 7;
  } else if (blk < 912) {        // Wq: [320][512] -> [512][320]
    const int tt = blk - 872;
    src = Wq; dst = Wq_t; RS = 320; CS = 512; kt = tt >> 3; ct = tt & 7;
  } else {                       // Wo: [512][320] -> [320][512]
    const int tt = blk - 912;
    src = Wo; dst = Wo_t; RS = 512; CS = 320; kt = tt / 5; ct = tt % 5;
  }
  const int cl = t & 63, rb = t >> 6;
  #pragma unroll
  for (int i = 0; i < 16; ++i)
    T[(rb + i*4)*65 + cl] = src[(size_t)(kt*64 + rb + i*4)*CS + ct*64 + cl];
  __syncthreads();
  #pragma unroll
  for (int i = 0; i < 16; ++i) {
    const int nl = rb + i*4;
    dst[(size_t)(ct*64 + nl)*RS + kt*64 + cl] = f2bf(T[cl*65 + nl]);
  }
}

// ---------------------------------------------------------------------------
// xpose: query [b][c][n] fp32 -> X_bf [b*4096+n][320] bf16 (64x64 tiles)
// ---------------------------------------------------------------------------
__global__ __launch_bounds__(256) void xpose_kernel(
    const float* __restrict__ query, short* __restrict__ X_bf) {
  __shared__ float T[64 * 65];
  const int bx = blockIdx.x, t = threadIdx.x;
  const int b = bx / 320, r = bx % 320;
  const int nt = r / 5, ct = r % 5;
  const int tl = t & 63, rb = t >> 6;
  #pragma unroll
  for (int i = 0; i < 16; ++i) {
    const int c = rb + i*4;
    T[c*65 + tl] = query[((size_t)(b*CC + ct*64 + c))*NN + nt*64 + tl];
  }
  __syncthreads();
  #pragma unroll
  for (int i = 0; i < 16; ++i) {
    const int n = rb + i*4;
    X_bf[((size_t)(b*NN + nt*64 + n))*CC + ct*64 + tl] = f2bf(T[tl*65 + n]);
  }
}

// ---------------------------------------------------------------------------
// kvproj: [616,1024]bf16 @ Wk_t/Wv_t -> K_ws [b][h][80][64], V_ws [b][h][64][96]
// ---------------------------------------------------------------------------
__global__ __launch_bounds__(256) void kvproj_kernel(
    const short* __restrict__ kv_bf, const short* __restrict__ Wk_t,
    const short* __restrict__ Wv_t, short* __restrict__ K_ws,
    short* __restrict__ V_ws) {
  const int t = threadIdx.x, w = t >> 6, lane = t & 63;
  const int l15 = lane & 15, q = lane >> 4;
  const int m0 = (blockIdx.x * 4 + w) * 16;
  const int y = blockIdx.y;
  const bool isK = (y < 8);
  const int h = y & 7;
  const short* __restrict__ Wt = isK ? Wk_t : Wv_t;
  const int arow = (m0 + l15 < 616) ? (m0 + l15) : 615;

  const f32x4 z = {0.f, 0.f, 0.f, 0.f};
  f32x4 acc[4] = {z, z, z, z};
  for (int k0 = 0; k0 < 1024; k0 += 32) {
    const bf16x8 a = *(const bf16x8*)(kv_bf + arow*1024 + k0 + q*8);
    #pragma unroll
    for (int nt = 0; nt < 4; ++nt) {
      const int n = h*64 + nt*16 + l15;
      const bf16x8 bfr = *(const bf16x8*)(Wt + n*1024 + k0 + q*8);
      acc[nt] = __builtin_amdgcn_mfma_f32_16x16x32_bf16(a, bfr, acc[nt], 0, 0, 0);
    }
  }
  #pragma unroll
  for (int nt = 0; nt < 4; ++nt) {
    const int d = nt*16 + l15;
    #pragma unroll
    for (int r = 0; r < 4; ++r) {
      const int row = m0 + q*4 + r;
      if (row < 616) {
        const int b = (int)(((unsigned)row * 54472u) >> 22);   // row/77
        const int s = row - b*77;
        if (isK) K_ws[((b*8 + h)*80 + s)*64 + d] = f2bf(acc[nt][r]);
        else     V_ws[((b*8 + h)*64 + d)*96 + s] = f2bf(acc[nt][r]);
      }
    }
  }
}

// ---------------------------------------------------------------------------
// qproj: X_bf [32768][320] @ Wq_t -> Q_ws [32768][512] bf16.
// Zero LDS. Wave job = 4 m-tiles x 4 n-tiles; all operands 16B-contiguous
// per-lane global loads (X from L3, Wq_t from L2). 4096 independent waves.
// ---------------------------------------------------------------------------
__global__ __launch_bounds__(256) void qproj_kernel(
    const short* __restrict__ X_bf, const short* __restrict__ Wq_t,
    short* __restrict__ Q_ws) {
  const int t = threadIdx.x, w = t >> 6, lane = t & 63;
  const int l15 = lane & 15, q = lane >> 4;
  const int job = blockIdx.x * 4 + w;
  const int m0 = (job >> 3) * 64;          // 0..32704
  const int n0 = (job & 7) * 64;           // 0..448

  const f32x4 z = {0.f, 0.f, 0.f, 0.f};
  f32x4 acc[4][4];
  #pragma unroll
  for (int mt = 0; mt < 4; ++mt)
    #pragma unroll
    for (int nt = 0; nt < 4; ++nt) acc[mt][nt] = z;

  #pragma unroll
  for (int ks = 0; ks < 10; ++ks) {
    const int k0 = ks * 32;
    bf16x8 a[4], bfr[4];
    #pragma unroll
    for (int mt = 0; mt < 4; ++mt)
      a[mt] = *(const bf16x8*)(X_bf + (size_t)(m0 + mt*16 + l15)*320 + k0 + q*8);
    #pragma unroll
    for (int nt = 0; nt < 4; ++nt)
      bfr[nt] = *(const bf16x8*)(Wq_t + (size_t)(n0 + nt*16 + l15)*320 + k0 + q*8);
    #pragma unroll
    for (int mt = 0; mt < 4; ++mt)
      #pragma unroll
      for (int nt = 0; nt < 4; ++nt)
        acc[mt][nt] = __builtin_amdgcn_mfma_f32_16x16x32_bf16(a[mt], bfr[nt], acc[mt][nt], 0, 0, 0);
  }
  // store D[tok][j]: row m0+mt*16+q*4+r, col n0+nt*16+l15 (32B segments/row)
  #pragma unroll
  for (int mt = 0; mt < 4; ++mt)
    #pragma unroll
    for (int r = 0; r < 4; ++r) {
      short* rowp = Q_ws + (size_t)(m0 + mt*16 + q*4 + r)*512 + n0;
      #pragma unroll
      for (int nt = 0; nt < 4; ++nt)
        rowp[nt*16 + l15] = f2bf(acc[mt][nt][r]);
    }
}

// ---------------------------------------------------------------------------
// attncore: ONE wave per block = 16 tokens x 1 head.
//   QK^T (A=K_ws direct, B=Q_ws rows direct) -> shfl softmax -> P via 3.3 KB
//   per-wave LDS -> PV (A=V_ws direct) -> packed 8B stores to O_ws[tok][j].
//   16384 independent waves; K/V (1.8 MB) L2-resident on every XCD.
// ---------------------------------------------------------------------------
__global__ __launch_bounds__(64) void attncore_kernel(
    const short* __restrict__ Q_ws, const short* __restrict__ K_ws,
    const short* __restrict__ V_ws, short* __restrict__ O_ws) {
  const int bx = blockIdx.x;
  const int h = bx & 7;
  const int g = bx >> 3;                   // global 16-token tile 0..2047
  const int b = g >> 8;
  const int n0 = (g & 255) * 16;
  const int lane = threadIdx.x;
  const int l15 = lane & 15, q = lane >> 4;

  __shared__ short scr[16 * 104];          // P scratch, 3328 B
  for (int i = lane; i < 16*104/2; i += 64) ((unsigned*)scr)[i] = 0u;
  short* srow = scr + l15 * 104;

  const short* __restrict__ Kh = K_ws + (size_t)(b*8 + h) * 80 * 64;
  const short* __restrict__ Vh = V_ws + (size_t)(b*8 + h) * 64 * 96;
  const size_t tokrow = (size_t)(b*NN + n0 + l15);

  const f32x4 z = {0.f, 0.f, 0.f, 0.f};
  // ---- QK^T: D[s][tok] ----
  f32x4 qk[5] = {z, z, z, z, z};
  #pragma unroll
  for (int f = 0; f < 2; ++f) {
    const bf16x8 bq = *(const bf16x8*)(Q_ws + tokrow*512 + h*64 + f*32 + q*8);
    #pragma unroll
    for (int st = 0; st < 5; ++st) {
      const bf16x8 a = *(const bf16x8*)(Kh + (st*16 + l15)*64 + f*32 + q*8);
      qk[st] = __builtin_amdgcn_mfma_f32_16x16x32_bf16(a, bq, qk[st], 0, 0, 0);
    }
  }

  // ---- softmax over s (tok=l15; s = st*16+q*4+r; quad shfl reduce) ----
  float mx = -1e30f;
  #pragma unroll
  for (int st = 0; st < 5; ++st)
    #pragma unroll
    for (int r = 0; r < 4; ++r) {
      const int s = st*16 + q*4 + r;
      const float vv = (s < SKV) ? qk[st][r] * SCALE : -1e30f;
      qk[st][r] = vv;
      mx = fmaxf(mx, vv);
    }
  mx = fmaxf(mx, __shfl_xor(mx, 16));
  mx = fmaxf(mx, __shfl_xor(mx, 32));
  float sum = 0.f;
  #pragma unroll
  for (int st = 0; st < 5; ++st)
    #pragma unroll
    for (int r = 0; r < 4; ++r) {
      const int s = st*16 + q*4 + r;
      const float e = (s < SKV) ? __expf(qk[st][r] - mx) : 0.f;
      qk[st][r] = e;
      sum += e;
    }
  sum += __shfl_xor(sum, 16);
  sum += __shfl_xor(sum, 32);
  const float inv = 1.0f / sum;
  #pragma unroll
  for (int st = 0; st < 5; ++st) {
    s16x4 pv;
    #pragma unroll
    for (int r = 0; r < 4; ++r) pv[r] = f2bf(qk[st][r] * inv);
    *(s16x4*)(srow + st*16 + q*4) = pv;    // cols 0..79; [80,96) stay 0
  }

  // ---- PV: D[d][tok] = V^T @ P^T ----
  f32x4 ov[4] = {z, z, z, z};
  #pragma unroll
  for (int f = 0; f < 3; ++f) {
    const bf16x8 bp = *(const bf16x8*)(srow + f*32 + q*8);
    #pragma unroll
    for (int dt = 0; dt < 4; ++dt) {
      const bf16x8 a = *(const bf16x8*)(Vh + (dt*16 + l15)*96 + f*32 + q*8);
      ov[dt] = __builtin_amdgcn_mfma_f32_16x16x32_bf16(a, bp, ov[dt], 0, 0, 0);
    }
  }
  // ---- store O_ws[tok][h*64+d]: 8B packs, 32B/row segments ----
  #pragma unroll
  for (int dt = 0; dt < 4; ++dt) {
    s16x4 pv;
    #pragma unroll
    for (int r = 0; r < 4; ++r) pv[r] = f2bf(ov[dt][r]);
    *(s16x4*)(O_ws + tokrow*512 + h*64 + dt*16 + q*4) = pv;
  }
}

// ---------------------------------------------------------------------------
// outproj: O_ws [32768][512] @ Wo_t -> out [b][c][n] + bias.
// Zero LDS. Wave job = 5 m-tiles (c) x 2 n-tiles (tok); A=Wo_t (L2),
// B=O_ws rows. D[c][tok] -> 64B-segment NCHW stores. 4096 waves.
// ---------------------------------------------------------------------------
__global__ __launch_bounds__(256) void outproj_kernel(
    const short* __restrict__ O_ws, const short* __restrict__ Wo_t,
    const float* __restrict__ bo, float* __restrict__ out) {
  const int t = threadIdx.x, w = t >> 6, lane = t & 63;
  const int l15 = lane & 15, q = lane >> 4;
  const int job = blockIdx.x * 4 + w;
  const int c0 = (job & 3) * 80;
  const int g0 = (job >> 2) * 32;          // global token base

  const f32x4 z = {0.f, 0.f, 0.f, 0.f};
  f32x4 acc[5][2];
  #pragma unroll
  for (int mt = 0; mt < 5; ++mt)
    #pragma unroll
    for (int nt = 0; nt < 2; ++nt) acc[mt][nt] = z;

  for (int ks = 0; ks < 16; ++ks) {
    const int k0 = ks * 32;
    bf16x8 a[5], bfr[2];
    #pragma unroll
    for (int mt = 0; mt < 5; ++mt)
      a[mt] = *(const bf16x8*)(Wo_t + (size_t)(c0 + mt*16 + l15)*512 + k0 + q*8);
    #pragma unroll
    for (int nt = 0; nt < 2; ++nt)
      bfr[nt] = *(const bf16x8*)(O_ws + (size_t)(g0 + nt*16 + l15)*512 + k0 + q*8);
    #pragma unroll
    for (int mt = 0; mt < 5; ++mt)
      #pragma unroll
      for (int nt = 0; nt < 2; ++nt)
        acc[mt][nt] = __builtin_amdgcn_mfma_f32_16x16x32_bf16(a[mt], bfr[nt], acc[mt][nt], 0, 0, 0);
  }
  const int b = g0 >> 12, n = g0 & 4095;
  #pragma unroll
  for (int mt = 0; mt < 5; ++mt)
    #pragma unroll
    for (int r = 0; r < 4; ++r) {
      const int c = c0 + mt*16 + q*4 + r;
      const float bv = bo[c];
      float* rowp = out + ((size_t)(b*CC + c))*NN + n;
      #pragma unroll
      for (int nt = 0; nt < 2; ++nt)
        rowp[nt*16 + l15] = acc[mt][nt][r] + bv;
    }
}

// ---------------------------------------------------------------------------
extern "C" void kernel_launch(void* const* d_in, const int* in_sizes, int n_in,
                              void* d_out, int out_size, void* d_ws, size_t ws_size,
                              hipStream_t stream) {
  const float* query = (const float*)d_in[0];
  const float* kv    = (const float*)d_in[1];
  const float* Wq    = (const float*)d_in[2];
  const float* Wk    = (const float*)d_in[3];
  const float* Wv    = (const float*)d_in[4];
  const float* Wo    = (const float*)d_in[5];
  const float* bo    = (const float*)d_in[6];
  float* out = (float*)d_out;

  char* p = (char*)d_ws;
  // persistent region
  short* K_ws  = (short*)(p);             //   819,200 B [8][8][80][64]
  short* V_ws  = (short*)(p +   819200);  //   983,040 B [8][8][64][96]
  short* Wq_t  = (short*)(p +  1802240);  //   327,680 B [512][320]
  short* Wo_t  = (short*)(p +  2129920);  //   327,680 B [320][512]
  short* Q_ws  = (short*)(p +  2457600);  // 33,554,432 B [32768][512]
  // region B: X_bf/kv_bf/Wk_t/Wv_t (dead after qproj) overlaid by O_ws
  char* pb = p + 36012032;
  short* X_bf  = (short*)(pb);            // 20,971,520 B [32768][320]
  short* kv_bf = (short*)(pb + 20971520); //  1,261,568 B [616][1024]
  short* Wk_t  = (short*)(pb + 22233088); //  1,048,576 B [512][1024]
  short* Wv_t  = (short*)(pb + 23281664); //  1,048,576 B [512][1024]
  short* O_ws  = (short*)(pb);            // 33,554,432 B [32768][512] (overlay)

  prep_kernel<<<1392, 256, 0, stream>>>(kv, Wk, Wv, Wq, Wo, kv_bf, Wk_t, Wv_t,
                                        Wq_t, Wo_t, (unsigned*)p);
  xpose_kernel<<<2560, 256, 0, stream>>>(query, X_bf);
  kvproj_kernel<<<dim3(10, 16), 256, 0, stream>>>(kv_bf, Wk_t, Wv_t, K_ws, V_ws);
  qproj_kernel<<<1024, 256, 0, stream>>>(X_bf, Wq_t, Q_ws);
  attncore_kernel<<<16384, 64, 0, stream>>>(Q_ws, K_ws, V_ws, O_ws);
  outproj_kernel<<<1024, 256, 0, stream>>>(O_ws, Wo_t, bo, out);
}

// Round 7
// 197.161 us; speedup vs baseline: 1.7487x; 1.3854x over previous
//
#include <hip/hip_runtime.h>
#include <hip/hip_bf16.h>
#include <stdint.h>

#define BB     8
#define CC     320
#define NN     4096
#define SKV    77
#define HEADS  8
#define INNER  512
#define SCALE  0.125f

typedef float f32x4  __attribute__((ext_vector_type(4)));
typedef short bf16x8 __attribute__((ext_vector_type(8)));
typedef short s16x4  __attribute__((ext_vector_type(4)));

static __device__ __forceinline__ short f2bf(float f) {
  unsigned u = __float_as_uint(f);
  return (short)((u + 0x7fffu + ((u >> 16) & 1u)) >> 16);
}

// async global->LDS 16B copy (CK-style addrspace casts); LDS dest is
// wave-uniform base + lane*16, global addr is per-lane.
static __device__ __forceinline__ void gll16(void* lds, const void* g) {
  auto gp = reinterpret_cast<const uint32_t __attribute__((address_space(1)))*>(
      reinterpret_cast<uintptr_t>(g));
  auto lp = reinterpret_cast<uint32_t __attribute__((address_space(3)))*>(
      reinterpret_cast<uintptr_t>(lds));
  __builtin_amdgcn_global_load_lds(gp, lp, 16, 0, 0);
}

// ---------------------------------------------------------------------------
// prep: kv->bf16 | Wk,Wv,Wq,Wo tiled transposes -> bf16 | zero K_ws/V_ws.
// blocks: [0,616) kv | [616,872) Wk/Wv 64x64 tiles | [872,912) Wq tiles |
// [912,952) Wo tiles | [952,1392) zero K_ws+V_ws (1,802,240 B)
// ---------------------------------------------------------------------------
__global__ __launch_bounds__(256) void prep_kernel(
    const float* __restrict__ kv, const float* __restrict__ Wk,
    const float* __restrict__ Wv, const float* __restrict__ Wq,
    const float* __restrict__ Wo, short* __restrict__ kv_bf,
    short* __restrict__ Wk_t, short* __restrict__ Wv_t,
    short* __restrict__ Wq_t, short* __restrict__ Wo_t,
    unsigned* __restrict__ zero_base) {
  __shared__ float T[64 * 65];
  const int blk = blockIdx.x, t = threadIdx.x;
  if (blk < 616) {
    const int base = blk * 1024;
    #pragma unroll
    for (int i = 0; i < 4; ++i) kv_bf[base + i*256 + t] = f2bf(kv[base + i*256 + t]);
    return;
  }
  if (blk >= 952) {
    const int base = (blk - 952) * 1024;
    #pragma unroll
    for (int i = 0; i < 4; ++i) zero_base[base + i*256 + t] = 0u;
    return;
  }
  const float* src; short* dst; int RS, CS, kt, ct;
  if (blk < 872) {               // Wk/Wv: [1024][512] -> [512][1024]
    const int tile = blk - 616;
    const bool isK = tile < 128;
    const int tt = isK ? tile : tile - 128;
    src = isK ? Wk : Wv; dst = isK ? Wk_t : Wv_t;
    RS = 1024; CS = 512; kt = tt >> 3; ct = tt & 7;
  } else if (blk < 912) {        // Wq: [320][512] -> [512][320]
    const int tt = blk - 872;
    src = Wq; dst = Wq_t; RS = 320; CS = 512; kt = tt >> 3; ct = tt & 7;
  } else {                       // Wo: [512][320] -> [320][512]
    const int tt = blk - 912;
    src = Wo; dst = Wo_t; RS = 512; CS = 320; kt = tt / 5; ct = tt % 5;
  }
  const int cl = t & 63, rb = t >> 6;
  #pragma unroll
  for (int i = 0; i < 16; ++i)
    T[(rb + i*4)*65 + cl] = src[(size_t)(kt*64 + rb + i*4)*CS + ct*64 + cl];
  __syncthreads();
  #pragma unroll
  for (int i = 0; i < 16; ++i) {
    const int nl = rb + i*4;
    dst[(size_t)(ct*64 + nl)*RS + kt*64 + cl] = f2bf(T[cl*65 + nl]);
  }
}

// ---------------------------------------------------------------------------
// xpose: query [b][c][n] fp32 -> X_bf [b*4096+n][320] bf16 (64x64 tiles)
// ---------------------------------------------------------------------------
__global__ __launch_bounds__(256) void xpose_kernel(
    const float* __restrict__ query, short* __restrict__ X_bf) {
  __shared__ float T[64 * 65];
  const int bx = blockIdx.x, t = threadIdx.x;
  const int b = bx / 320, r = bx % 320;
  const int nt = r / 5, ct = r % 5;
  const int tl = t & 63, rb = t >> 6;
  #pragma unroll
  for (int i = 0; i < 16; ++i) {
    const int c = rb + i*4;
    T[c*65 + tl] = query[((size_t)(b*CC + ct*64 + c))*NN + nt*64 + tl];
  }
  __syncthreads();
  #pragma unroll
  for (int i = 0; i < 16; ++i) {
    const int n = rb + i*4;
    X_bf[((size_t)(b*NN + nt*64 + n))*CC + ct*64 + tl] = f2bf(T[tl*65 + n]);
  }
}

// ---------------------------------------------------------------------------
// kvproj: [616,1024]bf16 @ Wk_t/Wv_t -> K_ws [b][h][80][64], V_ws [b][h][64][96]
// ---------------------------------------------------------------------------
__global__ __launch_bounds__(256) void kvproj_kernel(
    const short* __restrict__ kv_bf, const short* __restrict__ Wk_t,
    const short* __restrict__ Wv_t, short* __restrict__ K_ws,
    short* __restrict__ V_ws) {
  const int t = threadIdx.x, w = t >> 6, lane = t & 63;
  const int l15 = lane & 15, q = lane >> 4;
  const int m0 = (blockIdx.x * 4 + w) * 16;
  const int y = blockIdx.y;
  const bool isK = (y < 8);
  const int h = y & 7;
  const short* __restrict__ Wt = isK ? Wk_t : Wv_t;
  const int arow = (m0 + l15 < 616) ? (m0 + l15) : 615;

  const f32x4 z = {0.f, 0.f, 0.f, 0.f};
  f32x4 acc[4] = {z, z, z, z};
  for (int k0 = 0; k0 < 1024; k0 += 32) {
    const bf16x8 a = *(const bf16x8*)(kv_bf + arow*1024 + k0 + q*8);
    #pragma unroll
    for (int nt = 0; nt < 4; ++nt) {
      const int n = h*64 + nt*16 + l15;
      const bf16x8 bfr = *(const bf16x8*)(Wt + n*1024 + k0 + q*8);
      acc[nt] = __builtin_amdgcn_mfma_f32_16x16x32_bf16(a, bfr, acc[nt], 0, 0, 0);
    }
  }
  #pragma unroll
  for (int nt = 0; nt < 4; ++nt) {
    const int d = nt*16 + l15;
    #pragma unroll
    for (int r = 0; r < 4; ++r) {
      const int row = m0 + q*4 + r;
      if (row < 616) {
        const int b = (int)(((unsigned)row * 54472u) >> 22);   // row/77
        const int s = row - b*77;
        if (isK) K_ws[((b*8 + h)*80 + s)*64 + d] = f2bf(acc[nt][r]);
        else     V_ws[((b*8 + h)*64 + d)*96 + s] = f2bf(acc[nt][r]);
      }
    }
  }
}

// ---------------------------------------------------------------------------
// qproj: X_bf [32768][320] @ Wq_t[512][320] -> Q_ws [32768][512] bf16.
// m97-style: 128x128 tile, BK=32, LDS [rows][32] staged via global_load_lds
// width-16; wave = 4m x 4n 16x16 tiles. grid 1024 blocks.
// ---------------------------------------------------------------------------
__global__ __launch_bounds__(256) void qproj_kernel(
    const short* __restrict__ X_bf, const short* __restrict__ Wq_t,
    short* __restrict__ Q_ws) {
  const int t = threadIdx.x, w = t >> 6, lane = t & 63;
  const int l15 = lane & 15, q = lane >> 4;
  const int m0 = (blockIdx.x >> 2) * 128;
  const int n0 = (blockIdx.x & 3) * 128;
  const int wm = w & 1, wn = w >> 1;

  __shared__ short tile[8192];   // A[128][32] @0, B[128][32] @4096 (shorts)

  const f32x4 z = {0.f, 0.f, 0.f, 0.f};
  f32x4 acc[4][4];
  #pragma unroll
  for (int mt = 0; mt < 4; ++mt)
    #pragma unroll
    for (int nt = 0; nt < 4; ++nt) acc[mt][nt] = z;

  for (int it = 0; it < 10; ++it) {
    const int k0 = it * 32;
    if (it) __syncthreads();
    #pragma unroll
    for (int p = 0; p < 2; ++p) {
      const int f = p*256 + t, row = f >> 2, c4 = f & 3;
      gll16(tile + f*8, X_bf + (size_t)(m0 + row)*320 + k0 + c4*8);
    }
    #pragma unroll
    for (int p = 0; p < 2; ++p) {
      const int f = p*256 + t, row = f >> 2, c4 = f & 3;
      gll16(tile + 4096 + f*8, Wq_t + (size_t)(n0 + row)*320 + k0 + c4*8);
    }
    __syncthreads();
    bf16x8 a[4], bb[4];
    #pragma unroll
    for (int mt = 0; mt < 4; ++mt)
      a[mt] = *(const bf16x8*)(tile + (wm*64 + mt*16 + l15)*32 + q*8);
    #pragma unroll
    for (int nt = 0; nt < 4; ++nt)
      bb[nt] = *(const bf16x8*)(tile + 4096 + (wn*64 + nt*16 + l15)*32 + q*8);
    #pragma unroll
    for (int mt = 0; mt < 4; ++mt)
      #pragma unroll
      for (int nt = 0; nt < 4; ++nt)
        acc[mt][nt] = __builtin_amdgcn_mfma_f32_16x16x32_bf16(a[mt], bb[nt], acc[mt][nt], 0, 0, 0);
  }
  #pragma unroll
  for (int mt = 0; mt < 4; ++mt)
    #pragma unroll
    for (int r = 0; r < 4; ++r) {
      short* rowp = Q_ws + (size_t)(m0 + wm*64 + mt*16 + q*4 + r)*512 + n0 + wn*64;
      #pragma unroll
      for (int nt = 0; nt < 4; ++nt)
        rowp[nt*16 + l15] = f2bf(acc[mt][nt][r]);
    }
}

// ---------------------------------------------------------------------------
// attncore: ONE wave per block = 32 tokens (2 n-tiles) x 1 head.
//   QK^T (A=K_ws, B=Q_ws rows; A shared across n-tiles) -> shfl softmax x2 ->
//   P via LDS -> PV -> packed 8B stores to O_ws. 8192 independent waves.
// ---------------------------------------------------------------------------
__global__ __launch_bounds__(64) void attncore_kernel(
    const short* __restrict__ Q_ws, const short* __restrict__ K_ws,
    const short* __restrict__ V_ws, short* __restrict__ O_ws) {
  const int bx = blockIdx.x;
  const int h = bx & 7;
  const int g = bx >> 3;                   // 32-token tile 0..1023
  const int b = g >> 7;
  const int n0 = (g & 127) * 32;
  const int lane = threadIdx.x;
  const int l15 = lane & 15, q = lane >> 4;

  __shared__ short scr[32 * 104];          // P scratch, 6656 B
  for (int i = lane; i < 32*104/2; i += 64) ((unsigned*)scr)[i] = 0u;

  const short* __restrict__ Kh = K_ws + (size_t)(b*8 + h) * 80 * 64;
  const short* __restrict__ Vh = V_ws + (size_t)(b*8 + h) * 64 * 96;
  size_t tokrow[2];
  #pragma unroll
  for (int nt = 0; nt < 2; ++nt) tokrow[nt] = (size_t)(b*NN + n0 + nt*16 + l15);

  const f32x4 z = {0.f, 0.f, 0.f, 0.f};
  // ---- QK^T: D[s][tok] for both token tiles; K-fragments shared ----
  f32x4 qk[2][5];
  #pragma unroll
  for (int nt = 0; nt < 2; ++nt)
    #pragma unroll
    for (int st = 0; st < 5; ++st) qk[nt][st] = z;
  #pragma unroll
  for (int f = 0; f < 2; ++f) {
    bf16x8 bq[2];
    #pragma unroll
    for (int nt = 0; nt < 2; ++nt)
      bq[nt] = *(const bf16x8*)(Q_ws + tokrow[nt]*512 + h*64 + f*32 + q*8);
    #pragma unroll
    for (int st = 0; st < 5; ++st) {
      const bf16x8 a = *(const bf16x8*)(Kh + (st*16 + l15)*64 + f*32 + q*8);
      #pragma unroll
      for (int nt = 0; nt < 2; ++nt)
        qk[nt][st] = __builtin_amdgcn_mfma_f32_16x16x32_bf16(a, bq[nt], qk[nt][st], 0, 0, 0);
    }
  }

  // ---- softmax + P writes, per token tile ----
  #pragma unroll
  for (int nt = 0; nt < 2; ++nt) {
    float mx = -1e30f;
    #pragma unroll
    for (int st = 0; st < 5; ++st)
      #pragma unroll
      for (int r = 0; r < 4; ++r) {
        const int s = st*16 + q*4 + r;
        const float vv = (s < SKV) ? qk[nt][st][r] * SCALE : -1e30f;
        qk[nt][st][r] = vv;
        mx = fmaxf(mx, vv);
      }
    mx = fmaxf(mx, __shfl_xor(mx, 16));
    mx = fmaxf(mx, __shfl_xor(mx, 32));
    float sum = 0.f;
    #pragma unroll
    for (int st = 0; st < 5; ++st)
      #pragma unroll
      for (int r = 0; r < 4; ++r) {
        const int s = st*16 + q*4 + r;
        const float e = (s < SKV) ? __expf(qk[nt][st][r] - mx) : 0.f;
        qk[nt][st][r] = e;
        sum += e;
      }
    sum += __shfl_xor(sum, 16);
    sum += __shfl_xor(sum, 32);
    const float inv = 1.0f / sum;
    #pragma unroll
    for (int st = 0; st < 5; ++st) {
      s16x4 pv;
      #pragma unroll
      for (int r = 0; r < 4; ++r) pv[r] = f2bf(qk[nt][st][r] * inv);
      *(s16x4*)(scr + (nt*16 + l15)*104 + st*16 + q*4) = pv;
    }
  }

  // ---- PV: D[d][tok]; V-fragments shared across token tiles ----
  f32x4 ov[2][4];
  #pragma unroll
  for (int nt = 0; nt < 2; ++nt)
    #pragma unroll
    for (int dt = 0; dt < 4; ++dt) ov[nt][dt] = z;
  #pragma unroll
  for (int f = 0; f < 3; ++f) {
    bf16x8 bp[2];
    #pragma unroll
    for (int nt = 0; nt < 2; ++nt)
      bp[nt] = *(const bf16x8*)(scr + (nt*16 + l15)*104 + f*32 + q*8);
    #pragma unroll
    for (int dt = 0; dt < 4; ++dt) {
      const bf16x8 a = *(const bf16x8*)(Vh + (dt*16 + l15)*96 + f*32 + q*8);
      #pragma unroll
      for (int nt = 0; nt < 2; ++nt)
        ov[nt][dt] = __builtin_amdgcn_mfma_f32_16x16x32_bf16(a, bp[nt], ov[nt][dt], 0, 0, 0);
    }
  }
  #pragma unroll
  for (int nt = 0; nt < 2; ++nt)
    #pragma unroll
    for (int dt = 0; dt < 4; ++dt) {
      s16x4 pv;
      #pragma unroll
      for (int r = 0; r < 4; ++r) pv[r] = f2bf(ov[nt][dt][r]);
      *(s16x4*)(O_ws + tokrow[nt]*512 + h*64 + dt*16 + q*4) = pv;
    }
}

// ---------------------------------------------------------------------------
// outproj: out^T = Wo_t[320][512] @ O_ws^T -> out[b][c][n] + bias.
// m97-style: A=Wo_t BM=160, B=O_ws BN=128 tok, BK=32; wave = 5m x 4n.
// grid 512 blocks. Coalesced fp32 epilogue.
// ---------------------------------------------------------------------------
__global__ __launch_bounds__(256) void outproj_kernel(
    const short* __restrict__ O_ws, const short* __restrict__ Wo_t,
    const float* __restrict__ bo, float* __restrict__ out) {
  const int t = threadIdx.x, w = t >> 6, lane = t & 63;
  const int l15 = lane & 15, q = lane >> 4;
  const int c0 = (blockIdx.x & 1) * 160;
  const int t0 = (blockIdx.x >> 1) * 128;
  const int wm = w & 1, wn = w >> 1;

  __shared__ short tile[9216];   // A[160][32] @0 (5120 sh), B[128][32] @5120

  const f32x4 z = {0.f, 0.f, 0.f, 0.f};
  f32x4 acc[5][4];
  #pragma unroll
  for (int mt = 0; mt < 5; ++mt)
    #pragma unroll
    for (int nt = 0; nt < 4; ++nt) acc[mt][nt] = z;

  for (int it = 0; it < 16; ++it) {
    const int k0 = it * 32;
    if (it) __syncthreads();
    #pragma unroll
    for (int p = 0; p < 5; ++p) {
      const int f = p*256 + t;
      if (f < 1152) {
        const short* g;
        if (f < 640) {
          const int row = f >> 2, c4 = f & 3;
          g = Wo_t + (size_t)(c0 + row)*512 + k0 + c4*8;
        } else {
          const int f2 = f - 640, row = f2 >> 2, c4 = f2 & 3;
          g = O_ws + (size_t)(t0 + row)*512 + k0 + c4*8;
        }
        gll16(tile + f*8, g);
      }
    }
    __syncthreads();
    bf16x8 a[5], bb[4];
    #pragma unroll
    for (int mt = 0; mt < 5; ++mt)
      a[mt] = *(const bf16x8*)(tile + (wm*80 + mt*16 + l15)*32 + q*8);
    #pragma unroll
    for (int nt = 0; nt < 4; ++nt)
      bb[nt] = *(const bf16x8*)(tile + 5120 + (wn*64 + nt*16 + l15)*32 + q*8);
    #pragma unroll
    for (int mt = 0; mt < 5; ++mt)
      #pragma unroll
      for (int nt = 0; nt < 4; ++nt)
        acc[mt][nt] = __builtin_amdgcn_mfma_f32_16x16x32_bf16(a[mt], bb[nt], acc[mt][nt], 0, 0, 0);
  }
  const int b = t0 >> 12, n = t0 & 4095;
  #pragma unroll
  for (int mt = 0; mt < 5; ++mt)
    #pragma unroll
    for (int r = 0; r < 4; ++r) {
      const int c = c0 + wm*80 + mt*16 + q*4 + r;
      const float bv = bo[c];
      float* rowp = out + ((size_t)(b*CC + c))*NN + n + wn*64;
      #pragma unroll
      for (int nt = 0; nt < 4; ++nt)
        rowp[nt*16 + l15] = acc[mt][nt][r] + bv;
    }
}

// ---------------------------------------------------------------------------
extern "C" void kernel_launch(void* const* d_in, const int* in_sizes, int n_in,
                              void* d_out, int out_size, void* d_ws, size_t ws_size,
                              hipStream_t stream) {
  const float* query = (const float*)d_in[0];
  const float* kv    = (const float*)d_in[1];
  const float* Wq    = (const float*)d_in[2];
  const float* Wk    = (const float*)d_in[3];
  const float* Wv    = (const float*)d_in[4];
  const float* Wo    = (const float*)d_in[5];
  const float* bo    = (const float*)d_in[6];
  float* out = (float*)d_out;

  char* p = (char*)d_ws;
  // persistent region
  short* K_ws  = (short*)(p);             //   819,200 B [8][8][80][64]
  short* V_ws  = (short*)(p +   819200);  //   983,040 B [8][8][64][96]
  short* Wq_t  = (short*)(p +  1802240);  //   327,680 B [512][320]
  short* Wo_t  = (short*)(p +  2129920);  //   327,680 B [320][512]
  short* Q_ws  = (short*)(p +  2457600);  // 33,554,432 B [32768][512]
  // region B: X_bf/kv_bf/Wk_t/Wv_t (dead after qproj) overlaid by O_ws
  char* pb = p + 36012032;
  short* X_bf  = (short*)(pb);            // 20,971,520 B [32768][320]
  short* kv_bf = (short*)(pb + 20971520); //  1,261,568 B [616][1024]
  short* Wk_t  = (short*)(pb + 22233088); //  1,048,576 B [512][1024]
  short* Wv_t  = (short*)(pb + 23281664); //  1,048,576 B [512][1024]
  short* O_ws  = (short*)(pb);            // 33,554,432 B [32768][512] (overlay)

  prep_kernel<<<1392, 256, 0, stream>>>(kv, Wk, Wv, Wq, Wo, kv_bf, Wk_t, Wv_t,
                                        Wq_t, Wo_t, (unsigned*)p);
  xpose_kernel<<<2560, 256, 0, stream>>>(query, X_bf);
  kvproj_kernel<<<dim3(10, 16), 256, 0, stream>>>(kv_bf, Wk_t, Wv_t, K_ws, V_ws);
  qproj_kernel<<<1024, 256, 0, stream>>>(X_bf, Wq_t, Q_ws);
  attncore_kernel<<<8192, 64, 0, stream>>>(Q_ws, K_ws, V_ws, O_ws);
  outproj_kernel<<<512, 256, 0, stream>>>(O_ws, Wo_t, bo, out);
}

// Round 8
// 191.955 us; speedup vs baseline: 1.7962x; 1.0271x over previous
//
#include <hip/hip_runtime.h>
#include <hip/hip_bf16.h>
#include <stdint.h>

#define BB     8
#define CC     320
#define NN     4096
#define SKV    77
#define HEADS  8
#define INNER  512
#define SCALE  0.125f

typedef float f32x4  __attribute__((ext_vector_type(4)));
typedef short bf16x8 __attribute__((ext_vector_type(8)));
typedef short s16x4  __attribute__((ext_vector_type(4)));

static __device__ __forceinline__ short f2bf(float f) {
  unsigned u = __float_as_uint(f);
  return (short)((u + 0x7fffu + ((u >> 16) & 1u)) >> 16);
}

// async global->LDS 16B copy; LDS dest is wave-uniform base + lane*16.
static __device__ __forceinline__ void gll16(void* lds, const void* g) {
  auto gp = reinterpret_cast<const uint32_t __attribute__((address_space(1)))*>(
      reinterpret_cast<uintptr_t>(g));
  auto lp = reinterpret_cast<uint32_t __attribute__((address_space(3)))*>(
      reinterpret_cast<uintptr_t>(lds));
  __builtin_amdgcn_global_load_lds(gp, lp, 16, 0, 0);
}

// ---------------------------------------------------------------------------
// prep (+xpose merged): kv->bf16 | Wk,Wv,Wq(x SCALE),Wo tiled transposes |
// zero K_ws/V_ws | query -> X_bf 64x64 tiles.
// blocks: [0,616) kv | [616,872) Wk/Wv | [872,912) Wq | [912,952) Wo |
// [952,1392) zero | [1392,3952) xpose
// ---------------------------------------------------------------------------
__global__ __launch_bounds__(256) void prep_kernel(
    const float* __restrict__ kv, const float* __restrict__ Wk,
    const float* __restrict__ Wv, const float* __restrict__ Wq,
    const float* __restrict__ Wo, const float* __restrict__ query,
    short* __restrict__ kv_bf, short* __restrict__ Wk_t,
    short* __restrict__ Wv_t, short* __restrict__ Wq_t,
    short* __restrict__ Wo_t, short* __restrict__ X_bf,
    unsigned* __restrict__ zero_base) {
  __shared__ float T[64 * 65];
  const int blk = blockIdx.x, t = threadIdx.x;
  if (blk < 616) {
    const int base = blk * 1024;
    #pragma unroll
    for (int i = 0; i < 4; ++i) kv_bf[base + i*256 + t] = f2bf(kv[base + i*256 + t]);
    return;
  }
  if (blk >= 1392) {              // xpose: query [b][c][n] -> X_bf [b*N+n][320]
    const int blk2 = blk - 1392;
    const int b = blk2 / 320, r = blk2 % 320;
    const int nt = r / 5, ct = r % 5;
    const int tl = t & 63, rb = t >> 6;
    #pragma unroll
    for (int i = 0; i < 16; ++i) {
      const int c = rb + i*4;
      T[c*65 + tl] = query[((size_t)(b*CC + ct*64 + c))*NN + nt*64 + tl];
    }
    __syncthreads();
    #pragma unroll
    for (int i = 0; i < 16; ++i) {
      const int n = rb + i*4;
      X_bf[((size_t)(b*NN + nt*64 + n))*CC + ct*64 + tl] = f2bf(T[tl*65 + n]);
    }
    return;
  }
  if (blk >= 952) {
    const int base = (blk - 952) * 1024;
    #pragma unroll
    for (int i = 0; i < 4; ++i) zero_base[base + i*256 + t] = 0u;
    return;
  }
  const float* src; short* dst; int RS, CS, kt, ct; float scl = 1.0f;
  if (blk < 872) {               // Wk/Wv: [1024][512] -> [512][1024]
    const int tile = blk - 616;
    const bool isK = tile < 128;
    const int tt = isK ? tile : tile - 128;
    src = isK ? Wk : Wv; dst = isK ? Wk_t : Wv_t;
    RS = 1024; CS = 512; kt = tt >> 3; ct = tt & 7;
  } else if (blk < 912) {        // Wq: [320][512] -> [512][320], x SCALE
    const int tt = blk - 872;
    src = Wq; dst = Wq_t; RS = 320; CS = 512; kt = tt >> 3; ct = tt & 7;
    scl = SCALE;
  } else {                       // Wo: [512][320] -> [320][512]
    const int tt = blk - 912;
    src = Wo; dst = Wo_t; RS = 512; CS = 320; kt = tt / 5; ct = tt % 5;
  }
  const int cl = t & 63, rb = t >> 6;
  #pragma unroll
  for (int i = 0; i < 16; ++i)
    T[(rb + i*4)*65 + cl] = src[(size_t)(kt*64 + rb + i*4)*CS + ct*64 + cl];
  __syncthreads();
  #pragma unroll
  for (int i = 0; i < 16; ++i) {
    const int nl = rb + i*4;
    dst[(size_t)(ct*64 + nl)*RS + kt*64 + cl] = f2bf(T[cl*65 + nl] * scl);
  }
}

// ---------------------------------------------------------------------------
// kvproj: [616,1024]bf16 @ Wk_t/Wv_t -> K_ws [b][h][80][64], V_ws [b][h][64][96]
// ---------------------------------------------------------------------------
__global__ __launch_bounds__(256) void kvproj_kernel(
    const short* __restrict__ kv_bf, const short* __restrict__ Wk_t,
    const short* __restrict__ Wv_t, short* __restrict__ K_ws,
    short* __restrict__ V_ws) {
  const int t = threadIdx.x, w = t >> 6, lane = t & 63;
  const int l15 = lane & 15, q = lane >> 4;
  const int m0 = (blockIdx.x * 4 + w) * 16;
  const int y = blockIdx.y;
  const bool isK = (y < 8);
  const int h = y & 7;
  const short* __restrict__ Wt = isK ? Wk_t : Wv_t;
  const int arow = (m0 + l15 < 616) ? (m0 + l15) : 615;

  const f32x4 z = {0.f, 0.f, 0.f, 0.f};
  f32x4 acc[4] = {z, z, z, z};
  for (int k0 = 0; k0 < 1024; k0 += 32) {
    const bf16x8 a = *(const bf16x8*)(kv_bf + arow*1024 + k0 + q*8);
    #pragma unroll
    for (int nt = 0; nt < 4; ++nt) {
      const int n = h*64 + nt*16 + l15;
      const bf16x8 bfr = *(const bf16x8*)(Wt + n*1024 + k0 + q*8);
      acc[nt] = __builtin_amdgcn_mfma_f32_16x16x32_bf16(a, bfr, acc[nt], 0, 0, 0);
    }
  }
  #pragma unroll
  for (int nt = 0; nt < 4; ++nt) {
    const int d = nt*16 + l15;
    #pragma unroll
    for (int r = 0; r < 4; ++r) {
      const int row = m0 + q*4 + r;
      if (row < 616) {
        const int b = (int)(((unsigned)row * 54472u) >> 22);   // row/77
        const int s = row - b*77;
        if (isK) K_ws[((b*8 + h)*80 + s)*64 + d] = f2bf(acc[nt][r]);
        else     V_ws[((b*8 + h)*64 + d)*96 + s] = f2bf(acc[nt][r]);
      }
    }
  }
}

// ---------------------------------------------------------------------------
// qproj: X_bf [32768][320] @ Wq_t[512][320] -> Q_ws [32768][512] bf16.
// m97-style: BM=128, BN=256, BK=32; LDS staged via global_load_lds width-16.
// wave = 4m x 8n 16x16 tiles (64 tok x 128 j). grid 512 blocks = 2/CU.
// ---------------------------------------------------------------------------
__global__ __launch_bounds__(256, 2) void qproj_kernel(
    const short* __restrict__ X_bf, const short* __restrict__ Wq_t,
    short* __restrict__ Q_ws) {
  const int t = threadIdx.x, w = t >> 6, lane = t & 63;
  const int l15 = lane & 15, q = lane >> 4;
  const int m0 = (blockIdx.x >> 1) * 128;
  const int n0 = (blockIdx.x & 1) * 256;
  const int wm = w & 1, wn = w >> 1;       // wn in 0..1

  __shared__ short tile[12288];  // A[128][32] @0, B[256][32] @4096 (shorts)

  const f32x4 z = {0.f, 0.f, 0.f, 0.f};
  f32x4 acc[4][8];
  #pragma unroll
  for (int mt = 0; mt < 4; ++mt)
    #pragma unroll
    for (int nt = 0; nt < 8; ++nt) acc[mt][nt] = z;

  for (int it = 0; it < 10; ++it) {
    const int k0 = it * 32;
    if (it) __syncthreads();
    #pragma unroll
    for (int p = 0; p < 2; ++p) {
      const int f = p*256 + t, row = f >> 2, c4 = f & 3;
      gll16(tile + f*8, X_bf + (size_t)(m0 + row)*320 + k0 + c4*8);
    }
    #pragma unroll
    for (int p = 0; p < 4; ++p) {
      const int f = p*256 + t, row = f >> 2, c4 = f & 3;
      gll16(tile + 4096 + f*8, Wq_t + (size_t)(n0 + row)*320 + k0 + c4*8);
    }
    __syncthreads();
    bf16x8 a[4], bb[8];
    #pragma unroll
    for (int mt = 0; mt < 4; ++mt)
      a[mt] = *(const bf16x8*)(tile + (wm*64 + mt*16 + l15)*32 + q*8);
    #pragma unroll
    for (int nt = 0; nt < 8; ++nt)
      bb[nt] = *(const bf16x8*)(tile + 4096 + (wn*128 + nt*16 + l15)*32 + q*8);
    #pragma unroll
    for (int mt = 0; mt < 4; ++mt)
      #pragma unroll
      for (int nt = 0; nt < 8; ++nt)
        acc[mt][nt] = __builtin_amdgcn_mfma_f32_16x16x32_bf16(a[mt], bb[nt], acc[mt][nt], 0, 0, 0);
  }
  #pragma unroll
  for (int mt = 0; mt < 4; ++mt)
    #pragma unroll
    for (int r = 0; r < 4; ++r) {
      short* rowp = Q_ws + (size_t)(m0 + wm*64 + mt*16 + q*4 + r)*512 + n0 + wn*128;
      #pragma unroll
      for (int nt = 0; nt < 8; ++nt)
        rowp[nt*16 + l15] = f2bf(acc[mt][nt][r]);
    }
}

// ---------------------------------------------------------------------------
// attncore: 4 waves/block; each wave = 32 tokens (2 n-tiles) x 1 head,
// fully independent. Q pre-scaled by 0.125 (folded into Wq_t).
// QK^T (A=K_ws, B=Q_ws rows) -> shfl softmax x2 -> P via per-wave LDS ->
// PV -> packed 8B stores to O_ws. 8192 independent wave-units.
// ---------------------------------------------------------------------------
__global__ __launch_bounds__(256) void attncore_kernel(
    const short* __restrict__ Q_ws, const short* __restrict__ K_ws,
    const short* __restrict__ V_ws, short* __restrict__ O_ws) {
  const int t = threadIdx.x, w = t >> 6, lane = t & 63;
  const int unit = blockIdx.x * 4 + w;
  const int h = unit & 7;
  const int g = unit >> 3;                 // 32-token tile 0..1023
  const int b = g >> 7;
  const int n0 = (g & 127) * 32;
  const int l15 = lane & 15, q = lane >> 4;

  __shared__ short scr[4 * 32 * 104];      // per-wave P scratch
  short* scrw = scr + w * 32 * 104;
  for (int i = lane; i < 32*104/2; i += 64) ((unsigned*)scrw)[i] = 0u;

  const short* __restrict__ Kh = K_ws + (size_t)(b*8 + h) * 80 * 64;
  const short* __restrict__ Vh = V_ws + (size_t)(b*8 + h) * 64 * 96;
  size_t tokrow[2];
  #pragma unroll
  for (int nt = 0; nt < 2; ++nt) tokrow[nt] = (size_t)(b*NN + n0 + nt*16 + l15);

  const f32x4 z = {0.f, 0.f, 0.f, 0.f};
  f32x4 qk[2][5];
  #pragma unroll
  for (int nt = 0; nt < 2; ++nt)
    #pragma unroll
    for (int st = 0; st < 5; ++st) qk[nt][st] = z;
  #pragma unroll
  for (int f = 0; f < 2; ++f) {
    bf16x8 bq[2];
    #pragma unroll
    for (int nt = 0; nt < 2; ++nt)
      bq[nt] = *(const bf16x8*)(Q_ws + tokrow[nt]*512 + h*64 + f*32 + q*8);
    #pragma unroll
    for (int st = 0; st < 5; ++st) {
      const bf16x8 a = *(const bf16x8*)(Kh + (st*16 + l15)*64 + f*32 + q*8);
      #pragma unroll
      for (int nt = 0; nt < 2; ++nt)
        qk[nt][st] = __builtin_amdgcn_mfma_f32_16x16x32_bf16(a, bq[nt], qk[nt][st], 0, 0, 0);
    }
  }

  #pragma unroll
  for (int nt = 0; nt < 2; ++nt) {
    float mx = -1e30f;
    #pragma unroll
    for (int st = 0; st < 5; ++st)
      #pragma unroll
      for (int r = 0; r < 4; ++r) {
        const int s = st*16 + q*4 + r;
        const float vv = (s < SKV) ? qk[nt][st][r] : -1e30f;
        qk[nt][st][r] = vv;
        mx = fmaxf(mx, vv);
      }
    mx = fmaxf(mx, __shfl_xor(mx, 16));
    mx = fmaxf(mx, __shfl_xor(mx, 32));
    float sum = 0.f;
    #pragma unroll
    for (int st = 0; st < 5; ++st)
      #pragma unroll
      for (int r = 0; r < 4; ++r) {
        const int s = st*16 + q*4 + r;
        const float e = (s < SKV) ? __expf(qk[nt][st][r] - mx) : 0.f;
        qk[nt][st][r] = e;
        sum += e;
      }
    sum += __shfl_xor(sum, 16);
    sum += __shfl_xor(sum, 32);
    const float inv = 1.0f / sum;
    #pragma unroll
    for (int st = 0; st < 5; ++st) {
      s16x4 pv;
      #pragma unroll
      for (int r = 0; r < 4; ++r) pv[r] = f2bf(qk[nt][st][r] * inv);
      *(s16x4*)(scrw + (nt*16 + l15)*104 + st*16 + q*4) = pv;
    }
  }

  f32x4 ov[2][4];
  #pragma unroll
  for (int nt = 0; nt < 2; ++nt)
    #pragma unroll
    for (int dt = 0; dt < 4; ++dt) ov[nt][dt] = z;
  #pragma unroll
  for (int f = 0; f < 3; ++f) {
    bf16x8 bp[2];
    #pragma unroll
    for (int nt = 0; nt < 2; ++nt)
      bp[nt] = *(const bf16x8*)(scrw + (nt*16 + l15)*104 + f*32 + q*8);
    #pragma unroll
    for (int dt = 0; dt < 4; ++dt) {
      const bf16x8 a = *(const bf16x8*)(Vh + (dt*16 + l15)*96 + f*32 + q*8);
      #pragma unroll
      for (int nt = 0; nt < 2; ++nt)
        ov[nt][dt] = __builtin_amdgcn_mfma_f32_16x16x32_bf16(a, bp[nt], ov[nt][dt], 0, 0, 0);
    }
  }
  #pragma unroll
  for (int nt = 0; nt < 2; ++nt)
    #pragma unroll
    for (int dt = 0; dt < 4; ++dt) {
      s16x4 pv;
      #pragma unroll
      for (int r = 0; r < 4; ++r) pv[r] = f2bf(ov[nt][dt][r]);
      *(s16x4*)(O_ws + tokrow[nt]*512 + h*64 + dt*16 + q*4) = pv;
    }
}

// ---------------------------------------------------------------------------
// outproj: out^T = Wo_t[320][512] @ O_ws^T -> out[b][c][n] + bias.
// m97-style: A=Wo_t BM=160, B=O_ws BN=128 tok, BK=32; wave = 5m x 4n.
// grid 512 blocks. Coalesced fp32 epilogue.
// ---------------------------------------------------------------------------
__global__ __launch_bounds__(256) void outproj_kernel(
    const short* __restrict__ O_ws, const short* __restrict__ Wo_t,
    const float* __restrict__ bo, float* __restrict__ out) {
  const int t = threadIdx.x, w = t >> 6, lane = t & 63;
  const int l15 = lane & 15, q = lane >> 4;
  const int c0 = (blockIdx.x & 1) * 160;
  const int t0 = (blockIdx.x >> 1) * 128;
  const int wm = w & 1, wn = w >> 1;

  __shared__ short tile[9216];   // A[160][32] @0 (5120 sh), B[128][32] @5120

  const f32x4 z = {0.f, 0.f, 0.f, 0.f};
  f32x4 acc[5][4];
  #pragma unroll
  for (int mt = 0; mt < 5; ++mt)
    #pragma unroll
    for (int nt = 0; nt < 4; ++nt) acc[mt][nt] = z;

  for (int it = 0; it < 16; ++it) {
    const int k0 = it * 32;
    if (it) __syncthreads();
    #pragma unroll
    for (int p = 0; p < 5; ++p) {
      const int f = p*256 + t;
      if (f < 1152) {
        const short* g;
        if (f < 640) {
          const int row = f >> 2, c4 = f & 3;
          g = Wo_t + (size_t)(c0 + row)*512 + k0 + c4*8;
        } else {
          const int f2 = f - 640, row = f2 >> 2, c4 = f2 & 3;
          g = O_ws + (size_t)(t0 + row)*512 + k0 + c4*8;
        }
        gll16(tile + f*8, g);
      }
    }
    __syncthreads();
    bf16x8 a[5], bb[4];
    #pragma unroll
    for (int mt = 0; mt < 5; ++mt)
      a[mt] = *(const bf16x8*)(tile + (wm*80 + mt*16 + l15)*32 + q*8);
    #pragma unroll
    for (int nt = 0; nt < 4; ++nt)
      bb[nt] = *(const bf16x8*)(tile + 5120 + (wn*64 + nt*16 + l15)*32 + q*8);
    #pragma unroll
    for (int mt = 0; mt < 5; ++mt)
      #pragma unroll
      for (int nt = 0; nt < 4; ++nt)
        acc[mt][nt] = __builtin_amdgcn_mfma_f32_16x16x32_bf16(a[mt], bb[nt], acc[mt][nt], 0, 0, 0);
  }
  const int b = t0 >> 12, n = t0 & 4095;
  #pragma unroll
  for (int mt = 0; mt < 5; ++mt)
    #pragma unroll
    for (int r = 0; r < 4; ++r) {
      const int c = c0 + wm*80 + mt*16 + q*4 + r;
      const float bv = bo[c];
      float* rowp = out + ((size_t)(b*CC + c))*NN + n + wn*64;
      #pragma unroll
      for (int nt = 0; nt < 4; ++nt)
        rowp[nt*16 + l15] = acc[mt][nt][r] + bv;
    }
}

// ---------------------------------------------------------------------------
extern "C" void kernel_launch(void* const* d_in, const int* in_sizes, int n_in,
                              void* d_out, int out_size, void* d_ws, size_t ws_size,
                              hipStream_t stream) {
  const float* query = (const float*)d_in[0];
  const float* kv    = (const float*)d_in[1];
  const float* Wq    = (const float*)d_in[2];
  const float* Wk    = (const float*)d_in[3];
  const float* Wv    = (const float*)d_in[4];
  const float* Wo    = (const float*)d_in[5];
  const float* bo    = (const float*)d_in[6];
  float* out = (float*)d_out;

  char* p = (char*)d_ws;
  // persistent region
  short* K_ws  = (short*)(p);             //   819,200 B [8][8][80][64]
  short* V_ws  = (short*)(p +   819200);  //   983,040 B [8][8][64][96]
  short* Wq_t  = (short*)(p +  1802240);  //   327,680 B [512][320] (x SCALE)
  short* Wo_t  = (short*)(p +  2129920);  //   327,680 B [320][512]
  short* Q_ws  = (short*)(p +  2457600);  // 33,554,432 B [32768][512]
  // region B: X_bf/kv_bf/Wk_t/Wv_t (dead after qproj) overlaid by O_ws
  char* pb = p + 36012032;
  short* X_bf  = (short*)(pb);            // 20,971,520 B [32768][320]
  short* kv_bf = (short*)(pb + 20971520); //  1,261,568 B [616][1024]
  short* Wk_t  = (short*)(pb + 22233088); //  1,048,576 B [512][1024]
  short* Wv_t  = (short*)(pb + 23281664); //  1,048,576 B [512][1024]
  short* O_ws  = (short*)(pb);            // 33,554,432 B [32768][512] (overlay)

  prep_kernel<<<3952, 256, 0, stream>>>(kv, Wk, Wv, Wq, Wo, query, kv_bf,
                                        Wk_t, Wv_t, Wq_t, Wo_t, X_bf,
                                        (unsigned*)p);
  kvproj_kernel<<<dim3(10, 16), 256, 0, stream>>>(kv_bf, Wk_t, Wv_t, K_ws, V_ws);
  qproj_kernel<<<512, 256, 0, stream>>>(X_bf, Wq_t, Q_ws);
  attncore_kernel<<<2048, 256, 0, stream>>>(Q_ws, K_ws, V_ws, O_ws);
  outproj_kernel<<<512, 256, 0, stream>>>(O_ws, Wo_t, bo, out);
}